// Round 6
// baseline (541.626 us; speedup 1.0000x reference)
//
#include <hip/hip_runtime.h>
#include <math.h>

#define T_DIM 16384
#define A_DIM 128
#define K_DIM 128
#define N_STEPS 16
#define E_DIM 126
#define NSEQ 4

// step0: 16-atom x 256-t tiles -> 8 atiles x 64 ttiles = 512 tiles/seq
#define NPT0 512
#define TT 256
#define NTT 64
#define SS_LEN 383
#define PIDX(i) ((i) + ((i) >> 5))   // +1 pad per 32 dwords (step0 engine)

// ---- workspace float offsets (total 10,514,448 floats ~= 40.2 MiB) ----
#define WS_DU    0                         // 16384 f
#define WS_EMB   16384                     // 8192 f
#define WS_NORM  24576                     // 16 f
#define WS_PMAX  24592                     // 2048 u64 = 4096 f (8B aligned)
#define WS_G     28688                     // 128*128*128 = 2,097,152 f
#define WS_S     (28688 + 2097152)         // 4*128*16384 = 8,388,608 f

// order-preserving pack: bigger u64 == (bigger value, then smaller flat idx).
__device__ inline unsigned long long pack_vi(float v, int fi) {
    unsigned int b = __float_as_uint(v);
    b = (b & 0x80000000u) ? ~b : (b | 0x80000000u);
    return ((unsigned long long)b << 32) | (unsigned int)(~fi);
}
__device__ inline void unpack_vi(unsigned long long p, float* v, int* fi) {
    unsigned int lo = (unsigned int)(p & 0xffffffffu);
    unsigned int b = (unsigned int)(p >> 32);
    unsigned int fb = (b & 0x80000000u) ? (b & 0x7fffffffu) : ~b;
    *v = __uint_as_float(fb);
    *fi = (int)(~lo);
}
__device__ inline unsigned long long u64max(unsigned long long a, unsigned long long b) {
    return a > b ? a : b;
}

// ---------------------------------------------------------------------------
// du normalize (one block per atom)
__global__ __launch_bounds__(256) void k_prep(
    const float* __restrict__ d, float* __restrict__ du) {
    int blk = blockIdx.x, tid = threadIdx.x;
    __shared__ float s[128];
    float v = 0.0f;
    if (tid < 128) { v = d[blk * K_DIM + tid]; s[tid] = v * v; }
    __syncthreads();
    for (int off = 64; off > 0; off >>= 1) {
        if (tid < off) s[tid] += s[tid + off];
        __syncthreads();
    }
    if (tid < 128) du[blk * K_DIM + tid] = v / (sqrtf(s[0]) + 1e-8f);
}

// ---------------------------------------------------------------------------
// Gram cross-correlation: G[w][a][d] = sum_k du[a][k]*du[w][k+d], d in [0,128).
// For dt<0 use G[a][w][-dt]. Grid 256 = (w<<1 | a-half), 256 thr.
// Mapping d = idx>>6 (wave-uniform trip count), al = idx&63 (padded rows ->
// conflict-free broadcast reads).
__global__ __launch_bounds__(256) void k_gram(
    const float* __restrict__ du, float* __restrict__ G) {
    int w = blockIdx.x >> 1, ah = blockIdx.x & 1;
    int tid = threadIdx.x;
    __shared__ float sw[128];
    __shared__ float sa[64][129];
    if (tid < 128) sw[tid] = du[w * K_DIM + tid];
    for (int i = tid; i < 64 * 128; i += 256)
        sa[i >> 7][i & 127] = du[(ah * 64 + (i >> 7)) * K_DIM + (i & 127)];
    __syncthreads();
    for (int e = 0; e < 32; e++) {
        int idx = e * 256 + tid;            // 8192 = 64 al x 128 d
        int dsh = idx >> 6;                 // uniform per 64-lane wave
        int al = idx & 63;
        float s = 0.0f;
        for (int k = 0; k < 128 - dsh; k++)
            s = fmaf(sa[al][k], sw[k + dsh], s);
        G[w * (A_DIM * K_DIM) + (ah * 64 + al) * K_DIM + dsh] = s;
    }
}

// ---------------------------------------------------------------------------
// 16a x 256t step0 engine (R10/R11-proven fmaf order) + S store.
__device__ inline unsigned long long tile16s(
    const float* __restrict__ duP, const float* __restrict__ rsh,
    float* __restrict__ Sp,
    int L0, int a_lo, int t_lo, int tid, unsigned long long* red4) {
    float acc[4][4];
    #pragma unroll
    for (int i = 0; i < 4; i++)
        #pragma unroll
        for (int j = 0; j < 4; j++) acc[i][j] = 0.0f;
    float r[8];
    #pragma unroll
    for (int m = 0; m < 8; m++) r[m] = rsh[PIDX(L0 + m)];
    #pragma unroll 4
    for (int k = 0; k < K_DIM; k += 4) {
        float dA[4][4];
        #pragma unroll
        for (int i = 0; i < 4; i++)
            *(float4*)dA[i] = *(const float4*)(duP + i * K_DIM + k);
        #pragma unroll
        for (int dk = 0; dk < 4; dk++) {
            #pragma unroll
            for (int i = 0; i < 4; i++) {
                float s = dA[i][dk];
                #pragma unroll
                for (int j = 0; j < 4; j++)
                    acc[i][j] = fmaf(s, r[j + dk], acc[i][j]);
            }
        }
        r[0] = r[4]; r[1] = r[5]; r[2] = r[6]; r[3] = r[7];
        #pragma unroll
        for (int m = 0; m < 4; m++) r[4 + m] = rsh[PIDX(L0 + k + 8 + m)];
    }
    #pragma unroll
    for (int i = 0; i < 4; i++)     // materialize S (coalesced float4 rows)
        *(float4*)(Sp + (a_lo + i) * T_DIM + t_lo) = *(const float4*)acc[i];
    float bv = -INFINITY;
    int bi = 0x7fffffff;
    #pragma unroll
    for (int i = 0; i < 4; i++) {
        int aa = a_lo + i;
        #pragma unroll
        for (int j = 0; j < 4; j++) {
            int fi = aa * T_DIM + t_lo + j;
            float v = acc[i][j];
            if (v > bv || (v == bv && fi < bi)) { bv = v; bi = fi; }
        }
    }
    #pragma unroll
    for (int off = 32; off > 0; off >>= 1) {
        float v2 = __shfl_down(bv, off);
        int   i2 = __shfl_down(bi, off);
        if (v2 > bv || (v2 == bv && i2 < bi)) { bv = v2; bi = i2; }
    }
    if ((tid & 63) == 0) red4[tid >> 6] = pack_vi(bv, bi);
    __syncthreads();
    if (tid == 0) {
        unsigned long long m = red4[0];
        #pragma unroll
        for (int w2 = 1; w2 < 4; w2++) m = u64max(m, red4[w2]);
        red4[0] = m;
    }
    __syncthreads();
    return red4[0];
}

__global__ __launch_bounds__(256) void k_step0(
    const float* __restrict__ a, const float* __restrict__ b,
    const float* __restrict__ du, float* __restrict__ S,
    unsigned long long* __restrict__ pmax) {
    __shared__ float rsh[408];       // max PIDX read = PIDX(387) = 399
    __shared__ unsigned long long red4[4];
    int blk = blockIdx.x, tid = threadIdx.x;
    int seq = blk >> 9, idx = blk & 511;
    int a_base = (idx >> 6) * 16, t0 = (idx & 63) * TT;
    const float* x = (seq < 2 ? a : b) + (seq & 1) * T_DIM;
    for (int i = tid; i < SS_LEN; i += 256) {
        int t = t0 - 64 + i;
        rsh[PIDX(i)] = (t >= 0 && t < T_DIM) ? x[t] : 0.0f;
    }
    __syncthreads();
    int tg = tid & 63;
    int ag = __builtin_amdgcn_readfirstlane(tid >> 6);
    unsigned long long p = tile16s(du + (a_base + ag * 4) * K_DIM, rsh,
                                   S + seq * (A_DIM * T_DIM),
                                   4 * tg, a_base + ag * 4, t0 + 4 * tg,
                                   tid, red4);
    if (tid == 0) pmax[seq * NPT0 + idx] = p;
}

// ---------------------------------------------------------------------------
// Incremental MP: one block per sequence, 1024 threads. S maintained in
// global; per step: winner from 64-entry LDS tile-max table, emb write,
// telescoped norm update, then update+rescan of the <=2 affected tiles
// (S[a][t] -= v*C(w,a,t-wt) inside the 255-window; fresh per-tile max).
// Exact direct-sum path when the winner's recon window clips at a boundary.
__global__ __launch_bounds__(1024) void k_inc(
    const float* __restrict__ a, const float* __restrict__ b,
    const float* __restrict__ du, const float* __restrict__ G,
    float* __restrict__ S, const unsigned long long* __restrict__ pmax,
    const float* __restrict__ ae, float* __restrict__ emb,
    float* __restrict__ normsG) {
    __shared__ unsigned long long tm[64];
    __shared__ unsigned long long red[16];
    __shared__ float fred[16];
    __shared__ unsigned long long wsh;
    __shared__ float sn2;
    int seq = blockIdx.x, tid = threadIdx.x;
    const float* x = (seq < 2 ? a : b) + (seq & 1) * T_DIM;
    float* Ss = S + seq * (A_DIM * T_DIM);

    if (tid < 64) {                         // tile-max table from step0 pmax
        unsigned long long m = pmax[seq * NPT0 + tid];
        #pragma unroll
        for (int at = 1; at < 8; at++)
            m = u64max(m, pmax[seq * NPT0 + at * 64 + tid]);
        tm[tid] = m;
    }
    {                                       // ||x||^2
        float s = 0.0f;
        for (int t = tid; t < T_DIM; t += 1024) {
            float v = x[t]; s = fmaf(v, v, s);
        }
        #pragma unroll
        for (int off = 32; off > 0; off >>= 1) s += __shfl_down(s, off);
        if ((tid & 63) == 0) fred[tid >> 6] = s;
    }
    __syncthreads();
    if (tid == 0) {
        float t = 0.0f;
        for (int j = 0; j < 16; j++) t += fred[j];
        sn2 = t;
    }
    __syncthreads();

    for (int step = 0; step < N_STEPS; step++) {
        if (tid < 64) {                     // global winner
            unsigned long long m = tm[tid];
            #pragma unroll
            for (int off = 32; off > 0; off >>= 1)
                m = u64max(m, __shfl_down(m, off));
            if (tid == 0) wsh = m;
        }
        __syncthreads();
        float v; int fi;
        unpack_vi(wsh, &v, &fi);
        int w = fi >> 14, wt = fi & (T_DIM - 1);
        {                                   // embedding row
            float* e = emb + (seq * N_STEPS + step) * 128;
            int pos_idx = v > 0.0f ? wt : 0;
            int aidx = v > 0.0f ? w : 0;
            if (tid == 0) {
                e[0] = ((float)pos_idx / (float)(T_DIM - 1)) * 20.0f;
                e[1] = v;
            }
            if (tid >= 2 && tid < 128) e[tid] = ae[aidx * E_DIM + tid - 2];
        }
        if (tid < 128) {                    // Q_clip partials (2 full waves)
            int t_res = wt + tid - 64;
            float q = 0.0f;
            if (t_res >= 0 && t_res < T_DIM) {
                float dv = du[w * K_DIM + tid];
                q = dv * dv;
            }
            #pragma unroll
            for (int off = 32; off > 0; off >>= 1) q += __shfl_down(q, off);
            if ((tid & 63) == 0) fred[8 + (tid >> 6)] = q;
        }
        __syncthreads();
        if (tid == 0) {                     // ||res'||^2 = ||res||^2 - v^2(2-Q)
            float Q = fred[8] + fred[9];
            sn2 = sn2 - v * v * (2.0f - Q);
        }

        if (step < N_STEPS - 1) {
            int lo = wt - 127; if (lo < 0) lo = 0;
            int hi = wt + 127; if (hi > T_DIM - 1) hi = T_DIM - 1;
            int Tlo = lo >> 8, Thi = hi >> 8;
            bool edge = (wt < 64) || (wt > T_DIM - 65);
            for (int Tt = Tlo; Tt <= Thi; Tt++) {
                unsigned long long mym = 0ULL;
                #pragma unroll 4
                for (int i = 0; i < 32; i++) {
                    int idx = i * 1024 + tid;          // 32768 = 128a x 256t
                    int aa = idx >> 8;
                    int tg = (Tt << 8) + (idx & 255);
                    float sval = Ss[aa * T_DIM + tg];
                    int dt = tg - wt;
                    if (dt >= -127 && dt <= 127) {
                        float c;
                        if (!edge) {
                            int neg = dt < 0;
                            int r0 = neg ? aa : w;
                            int r1 = neg ? w : aa;
                            int dd = neg ? -dt : dt;
                            c = G[r0 * (A_DIM * K_DIM) + r1 * K_DIM + dd];
                        } else {
                            // exact clipped correlation:
                            // sum_j du[w][j]*du[aa][j-dt], j in valid range
                            int jlo = dt > 0 ? dt : 0;
                            { int bnd = 64 - wt; if (bnd > jlo) jlo = bnd; }
                            int jhi = dt + 127; if (jhi > 127) jhi = 127;
                            { int bnd = T_DIM + 63 - wt; if (bnd < jhi) jhi = bnd; }
                            float dsum = 0.0f;
                            for (int j = jlo; j <= jhi; j++)
                                dsum = fmaf(du[w * K_DIM + j],
                                            du[aa * K_DIM + j - dt], dsum);
                            c = dsum;
                        }
                        sval = __fsub_rn(sval, __fmul_rn(v, c));
                        Ss[aa * T_DIM + tg] = sval;
                    }
                    unsigned long long pk = pack_vi(sval, aa * T_DIM + tg);
                    if (pk > mym) mym = pk;
                }
                #pragma unroll
                for (int off = 32; off > 0; off >>= 1)
                    mym = u64max(mym, __shfl_down(mym, off));
                if ((tid & 63) == 0) red[tid >> 6] = mym;
                __syncthreads();
                if (tid < 64) {
                    unsigned long long m2 = (tid < 16) ? red[tid] : 0ULL;
                    #pragma unroll
                    for (int off = 8; off > 0; off >>= 1)
                        m2 = u64max(m2, __shfl_down(m2, off));
                    if (tid == 0) tm[Tt] = m2;
                }
                __syncthreads();
            }
        }
    }
    if (tid == 0) normsG[seq] = sqrtf(sn2);
}

// ---------------------------------------------------------------------------
__global__ __launch_bounds__(256) void k_tail(
    const float* __restrict__ emb, const float* __restrict__ normsG,
    const float* __restrict__ proj, float* __restrict__ out) {
    __shared__ float keys[64];
    __shared__ int order[64];
    __shared__ float sh[256];
    __shared__ float norms[4];
    int tid = threadIdx.x;
    if (tid < NSEQ) norms[tid] = normsG[tid];
    if (tid < 64) {
        int seq = tid >> 4, st = tid & 15;
        const float* e = emb + (seq * N_STEPS + st) * 128;
        float kk = 0.0f;
        for (int dd = 0; dd < 128; dd++) kk = fmaf(e[dd], proj[dd], kk);
        keys[tid] = kk;
    }
    __syncthreads();
    if (tid < NSEQ) {
        int ord[N_STEPS];
        for (int i = 0; i < N_STEPS; i++) ord[i] = i;
        for (int i = 1; i < N_STEPS; i++) {     // stable ascending
            int oi = ord[i];
            float kv = keys[tid * N_STEPS + oi];
            int j = i - 1;
            while (j >= 0 && keys[tid * N_STEPS + ord[j]] > kv) {
                ord[j + 1] = ord[j]; j--;
            }
            ord[j + 1] = oi;
        }
        for (int i = 0; i < N_STEPS; i++) order[tid * N_STEPS + i] = ord[i];
    }
    __syncthreads();
    float s = 0.0f;
    #pragma unroll
    for (int t = 0; t < 16; t++) {
        int idx = tid + t * 256;
        int bq = idx >> 11;
        int st = (idx >> 7) & 15;
        int dd = idx & 127;
        float va = emb[((bq    ) * N_STEPS + order[bq * N_STEPS + st]) * 128 + dd];
        float vb = emb[((2 + bq) * N_STEPS + order[(2 + bq) * N_STEPS + st]) * 128 + dd];
        float df = va - vb;
        s = fmaf(df, df, s);
    }
    sh[tid] = s;
    __syncthreads();
    for (int off = 128; off > 0; off >>= 1) {
        if (tid < off) sh[tid] += sh[tid + off];
        __syncthreads();
    }
    if (tid == 0) {
        float mse = sh[0] / 4096.0f;
        float mad = 0.5f * (fabsf(norms[0] - norms[2]) + fabsf(norms[1] - norms[3]));
        out[0] = mse + mad;
    }
}

// ---------------------------------------------------------------------------
extern "C" void kernel_launch(void* const* d_in, const int* in_sizes, int n_in,
                              void* d_out, int out_size, void* d_ws, size_t ws_size,
                              hipStream_t stream) {
    const float* a    = (const float*)d_in[0];
    const float* b    = (const float*)d_in[1];
    const float* d    = (const float*)d_in[2];
    const float* ae   = (const float*)d_in[3];
    const float* proj = (const float*)d_in[4];
    float* out = (float*)d_out;

    float* ws     = (float*)d_ws;            // needs ~40.2 MiB
    float* du     = ws + WS_DU;
    float* emb    = ws + WS_EMB;
    float* normsG = ws + WS_NORM;
    unsigned long long* pmax = (unsigned long long*)(ws + WS_PMAX);
    float* G      = ws + WS_G;
    float* S      = ws + WS_S;

    k_prep <<<128,  256, 0, stream>>>(d, du);
    k_gram <<<256,  256, 0, stream>>>(du, G);
    k_step0<<<2048, 256, 0, stream>>>(a, b, du, S, pmax);
    k_inc  <<<4,   1024, 0, stream>>>(a, b, du, G, S, pmax, ae, emb, normsG);
    k_tail <<<1,    256, 0, stream>>>(emb, normsG, proj, out);
}

// Round 7
// 534.684 us; speedup vs baseline: 1.0130x; 1.0130x over previous
//
#include <hip/hip_runtime.h>
#include <math.h>

#define T_DIM 16384
#define A_DIM 128
#define K_DIM 128
#define N_STEPS 16
#define E_DIM 126
#define NSEQ 4

// step0: 16-atom x 256-t tiles -> 8 atiles x 64 ttiles = 512 tiles/seq
#define NPT0 512
#define TT 256
#define NTT 64
#define SS_LEN 383
#define PIDX(i) ((i) + ((i) >> 5))   // +1 pad per 32 dwords (step0 engine)

// ---- workspace float offsets (total 10,514,448 floats ~= 40.2 MiB) ----
#define WS_DU    0                         // 16384 f
#define WS_EMB   16384                     // 8192 f
#define WS_NORM  24576                     // 16 f
#define WS_PMAX  24592                     // 2048 u64 = 4096 f (8B aligned)
#define WS_G     28688                     // 128*128*128 = 2,097,152 f
#define WS_S     (28688 + 2097152)         // 4*128*16384 = 8,388,608 f

// order-preserving pack: bigger u64 == (bigger value, then smaller flat idx).
__device__ inline unsigned long long pack_vi(float v, int fi) {
    unsigned int b = __float_as_uint(v);
    b = (b & 0x80000000u) ? ~b : (b | 0x80000000u);
    return ((unsigned long long)b << 32) | (unsigned int)(~fi);
}
__device__ inline void unpack_vi(unsigned long long p, float* v, int* fi) {
    unsigned int lo = (unsigned int)(p & 0xffffffffu);
    unsigned int b = (unsigned int)(p >> 32);
    unsigned int fb = (b & 0x80000000u) ? (b & 0x7fffffffu) : ~b;
    *v = __uint_as_float(fb);
    *fi = (int)(~lo);
}
__device__ inline unsigned long long u64max(unsigned long long a, unsigned long long b) {
    return a > b ? a : b;
}

// ---------------------------------------------------------------------------
// du normalize (one block per atom)
__global__ __launch_bounds__(256) void k_prep(
    const float* __restrict__ d, float* __restrict__ du) {
    int blk = blockIdx.x, tid = threadIdx.x;
    __shared__ float s[128];
    float v = 0.0f;
    if (tid < 128) { v = d[blk * K_DIM + tid]; s[tid] = v * v; }
    __syncthreads();
    for (int off = 64; off > 0; off >>= 1) {
        if (tid < off) s[tid] += s[tid + off];
        __syncthreads();
    }
    if (tid < 128) du[blk * K_DIM + tid] = v / (sqrtf(s[0]) + 1e-8f);
}

// ---------------------------------------------------------------------------
// Gram cross-correlation: G[w][a][d] = sum_k du[a][k]*du[w][k+d], d in [0,128).
// For dt<0 use G[a][w][-dt]. Grid 256 = (w<<1 | a-half), 256 thr.
__global__ __launch_bounds__(256) void k_gram(
    const float* __restrict__ du, float* __restrict__ G) {
    int w = blockIdx.x >> 1, ah = blockIdx.x & 1;
    int tid = threadIdx.x;
    __shared__ float sw[128];
    __shared__ float sa[64][129];
    if (tid < 128) sw[tid] = du[w * K_DIM + tid];
    for (int i = tid; i < 64 * 128; i += 256)
        sa[i >> 7][i & 127] = du[(ah * 64 + (i >> 7)) * K_DIM + (i & 127)];
    __syncthreads();
    for (int e = 0; e < 32; e++) {
        int idx = e * 256 + tid;            // 8192 = 64 al x 128 d
        int dsh = idx >> 6;                 // uniform per 64-lane wave
        int al = idx & 63;
        float s = 0.0f;
        for (int k = 0; k < 128 - dsh; k++)
            s = fmaf(sa[al][k], sw[k + dsh], s);
        G[w * (A_DIM * K_DIM) + (ah * 64 + al) * K_DIM + dsh] = s;
    }
}

// ---------------------------------------------------------------------------
// 16a x 256t step0 engine (R10/R11-proven fmaf order) + S store.
__device__ inline unsigned long long tile16s(
    const float* __restrict__ duP, const float* __restrict__ rsh,
    float* __restrict__ Sp,
    int L0, int a_lo, int t_lo, int tid, unsigned long long* red4) {
    float acc[4][4];
    #pragma unroll
    for (int i = 0; i < 4; i++)
        #pragma unroll
        for (int j = 0; j < 4; j++) acc[i][j] = 0.0f;
    float r[8];
    #pragma unroll
    for (int m = 0; m < 8; m++) r[m] = rsh[PIDX(L0 + m)];
    #pragma unroll 4
    for (int k = 0; k < K_DIM; k += 4) {
        float dA[4][4];
        #pragma unroll
        for (int i = 0; i < 4; i++)
            *(float4*)dA[i] = *(const float4*)(duP + i * K_DIM + k);
        #pragma unroll
        for (int dk = 0; dk < 4; dk++) {
            #pragma unroll
            for (int i = 0; i < 4; i++) {
                float s = dA[i][dk];
                #pragma unroll
                for (int j = 0; j < 4; j++)
                    acc[i][j] = fmaf(s, r[j + dk], acc[i][j]);
            }
        }
        r[0] = r[4]; r[1] = r[5]; r[2] = r[6]; r[3] = r[7];
        #pragma unroll
        for (int m = 0; m < 4; m++) r[4 + m] = rsh[PIDX(L0 + k + 8 + m)];
    }
    #pragma unroll
    for (int i = 0; i < 4; i++)     // materialize S (coalesced float4 rows)
        *(float4*)(Sp + (a_lo + i) * T_DIM + t_lo) = *(const float4*)acc[i];
    float bv = -INFINITY;
    int bi = 0x7fffffff;
    #pragma unroll
    for (int i = 0; i < 4; i++) {
        int aa = a_lo + i;
        #pragma unroll
        for (int j = 0; j < 4; j++) {
            int fi = aa * T_DIM + t_lo + j;
            float v = acc[i][j];
            if (v > bv || (v == bv && fi < bi)) { bv = v; bi = fi; }
        }
    }
    #pragma unroll
    for (int off = 32; off > 0; off >>= 1) {
        float v2 = __shfl_down(bv, off);
        int   i2 = __shfl_down(bi, off);
        if (v2 > bv || (v2 == bv && i2 < bi)) { bv = v2; bi = i2; }
    }
    if ((tid & 63) == 0) red4[tid >> 6] = pack_vi(bv, bi);
    __syncthreads();
    if (tid == 0) {
        unsigned long long m = red4[0];
        #pragma unroll
        for (int w2 = 1; w2 < 4; w2++) m = u64max(m, red4[w2]);
        red4[0] = m;
    }
    __syncthreads();
    return red4[0];
}

__global__ __launch_bounds__(256) void k_step0(
    const float* __restrict__ a, const float* __restrict__ b,
    const float* __restrict__ du, float* __restrict__ S,
    unsigned long long* __restrict__ pmax) {
    __shared__ float rsh[408];       // max PIDX read = PIDX(387) = 399
    __shared__ unsigned long long red4[4];
    int blk = blockIdx.x, tid = threadIdx.x;
    int seq = blk >> 9, idx = blk & 511;
    int a_base = (idx >> 6) * 16, t0 = (idx & 63) * TT;
    const float* x = (seq < 2 ? a : b) + (seq & 1) * T_DIM;
    for (int i = tid; i < SS_LEN; i += 256) {
        int t = t0 - 64 + i;
        rsh[PIDX(i)] = (t >= 0 && t < T_DIM) ? x[t] : 0.0f;
    }
    __syncthreads();
    int tg = tid & 63;
    int ag = __builtin_amdgcn_readfirstlane(tid >> 6);
    unsigned long long p = tile16s(du + (a_base + ag * 4) * K_DIM, rsh,
                                   S + seq * (A_DIM * T_DIM),
                                   4 * tg, a_base + ag * 4, t0 + 4 * tg,
                                   tid, red4);
    if (tid == 0) pmax[seq * NPT0 + idx] = p;
}

// ---------------------------------------------------------------------------
// Incremental MP: one block per sequence, 1024 threads. R20: the tile-scan
// loop is restructured into 4 explicit batches of 8 elements with all S and
// G loads issued up front (16 loads in flight/thread). R19's VGPR=24 build
// serialized one ~450cyc LLC round-trip per element -> 406 us; same math,
// same update set, same fmaf order per element (bit-identical results).
__global__ __launch_bounds__(1024) void k_inc(
    const float* __restrict__ a, const float* __restrict__ b,
    const float* __restrict__ du, const float* __restrict__ G,
    float* __restrict__ S, const unsigned long long* __restrict__ pmax,
    const float* __restrict__ ae, float* __restrict__ emb,
    float* __restrict__ normsG) {
    __shared__ unsigned long long tm[64];
    __shared__ unsigned long long red[16];
    __shared__ float fred[16];
    __shared__ unsigned long long wsh;
    __shared__ float sn2;
    int seq = blockIdx.x, tid = threadIdx.x;
    const float* x = (seq < 2 ? a : b) + (seq & 1) * T_DIM;
    float* Ss = S + seq * (A_DIM * T_DIM);

    if (tid < 64) {                         // tile-max table from step0 pmax
        unsigned long long m = pmax[seq * NPT0 + tid];
        #pragma unroll
        for (int at = 1; at < 8; at++)
            m = u64max(m, pmax[seq * NPT0 + at * 64 + tid]);
        tm[tid] = m;
    }
    {                                       // ||x||^2
        float s = 0.0f;
        for (int t = tid; t < T_DIM; t += 1024) {
            float v = x[t]; s = fmaf(v, v, s);
        }
        #pragma unroll
        for (int off = 32; off > 0; off >>= 1) s += __shfl_down(s, off);
        if ((tid & 63) == 0) fred[tid >> 6] = s;
    }
    __syncthreads();
    if (tid == 0) {
        float t = 0.0f;
        for (int j = 0; j < 16; j++) t += fred[j];
        sn2 = t;
    }
    __syncthreads();

    for (int step = 0; step < N_STEPS; step++) {
        if (tid < 64) {                     // global winner
            unsigned long long m = tm[tid];
            #pragma unroll
            for (int off = 32; off > 0; off >>= 1)
                m = u64max(m, __shfl_down(m, off));
            if (tid == 0) wsh = m;
        }
        __syncthreads();
        float v; int fi;
        unpack_vi(wsh, &v, &fi);
        int w = fi >> 14, wt = fi & (T_DIM - 1);
        {                                   // embedding row
            float* e = emb + (seq * N_STEPS + step) * 128;
            int pos_idx = v > 0.0f ? wt : 0;
            int aidx = v > 0.0f ? w : 0;
            if (tid == 0) {
                e[0] = ((float)pos_idx / (float)(T_DIM - 1)) * 20.0f;
                e[1] = v;
            }
            if (tid >= 2 && tid < 128) e[tid] = ae[aidx * E_DIM + tid - 2];
        }
        if (tid < 128) {                    // Q_clip partials (2 full waves)
            int t_res = wt + tid - 64;
            float q = 0.0f;
            if (t_res >= 0 && t_res < T_DIM) {
                float dv = du[w * K_DIM + tid];
                q = dv * dv;
            }
            #pragma unroll
            for (int off = 32; off > 0; off >>= 1) q += __shfl_down(q, off);
            if ((tid & 63) == 0) fred[8 + (tid >> 6)] = q;
        }
        __syncthreads();
        if (tid == 0) {                     // ||res'||^2 = ||res||^2 - v^2(2-Q)
            float Q = fred[8] + fred[9];
            sn2 = sn2 - v * v * (2.0f - Q);
        }

        if (step < N_STEPS - 1) {
            int lo = wt - 127; if (lo < 0) lo = 0;
            int hi = wt + 127; if (hi > T_DIM - 1) hi = T_DIM - 1;
            int Tlo = lo >> 8, Thi = hi >> 8;
            bool edge = (wt < 64) || (wt > T_DIM - 65);
            for (int Tt = Tlo; Tt <= Thi; Tt++) {
                unsigned long long mym = 0ULL;
                #pragma unroll
                for (int g = 0; g < 4; g++) {      // 4 batches x 8 elements
                    float sv[8], cv[8];
                    int  aa8[8], tg8[8];
                    bool upd[8];
                    #pragma unroll
                    for (int u = 0; u < 8; u++) {  // issue 16 loads, no use
                        int idx = (g * 8 + u) * 1024 + tid;   // 128a x 256t
                        int aa = idx >> 8;
                        int tg = (Tt << 8) + (idx & 255);
                        aa8[u] = aa; tg8[u] = tg;
                        sv[u] = Ss[aa * T_DIM + tg];
                        int dt = tg - wt;
                        upd[u] = (dt >= -127 && dt <= 127);
                        int neg = dt < 0;
                        int r0 = neg ? aa : w;
                        int r1 = neg ? w : aa;
                        int dd = neg ? -dt : dt;
                        if (dd > 127) dd = 127;    // clamp: safe dummy addr
                        cv[u] = G[r0 * (A_DIM * K_DIM) + r1 * K_DIM + dd];
                    }
                    #pragma unroll
                    for (int u = 0; u < 8; u++) {
                        if (upd[u]) {
                            float c = cv[u];
                            if (edge) {
                                // exact clipped correlation:
                                // sum_j du[w][j]*du[aa][j-dt], valid j
                                int dt = tg8[u] - wt;
                                int jlo = dt > 0 ? dt : 0;
                                { int bnd = 64 - wt; if (bnd > jlo) jlo = bnd; }
                                int jhi = dt + 127; if (jhi > 127) jhi = 127;
                                { int bnd = T_DIM + 63 - wt; if (bnd < jhi) jhi = bnd; }
                                float dsum = 0.0f;
                                for (int j = jlo; j <= jhi; j++)
                                    dsum = fmaf(du[w * K_DIM + j],
                                                du[aa8[u] * K_DIM + j - dt], dsum);
                                c = dsum;
                            }
                            sv[u] = __fsub_rn(sv[u], __fmul_rn(v, c));
                            Ss[aa8[u] * T_DIM + tg8[u]] = sv[u];
                        }
                        unsigned long long pk =
                            pack_vi(sv[u], aa8[u] * T_DIM + tg8[u]);
                        if (pk > mym) mym = pk;
                    }
                }
                #pragma unroll
                for (int off = 32; off > 0; off >>= 1)
                    mym = u64max(mym, __shfl_down(mym, off));
                if ((tid & 63) == 0) red[tid >> 6] = mym;
                __syncthreads();
                if (tid < 64) {
                    unsigned long long m2 = (tid < 16) ? red[tid] : 0ULL;
                    #pragma unroll
                    for (int off = 8; off > 0; off >>= 1)
                        m2 = u64max(m2, __shfl_down(m2, off));
                    if (tid == 0) tm[Tt] = m2;
                }
                __syncthreads();
            }
        }
    }
    if (tid == 0) normsG[seq] = sqrtf(sn2);
}

// ---------------------------------------------------------------------------
__global__ __launch_bounds__(256) void k_tail(
    const float* __restrict__ emb, const float* __restrict__ normsG,
    const float* __restrict__ proj, float* __restrict__ out) {
    __shared__ float keys[64];
    __shared__ int order[64];
    __shared__ float sh[256];
    __shared__ float norms[4];
    int tid = threadIdx.x;
    if (tid < NSEQ) norms[tid] = normsG[tid];
    if (tid < 64) {
        int seq = tid >> 4, st = tid & 15;
        const float* e = emb + (seq * N_STEPS + st) * 128;
        float kk = 0.0f;
        for (int dd = 0; dd < 128; dd++) kk = fmaf(e[dd], proj[dd], kk);
        keys[tid] = kk;
    }
    __syncthreads();
    if (tid < NSEQ) {
        int ord[N_STEPS];
        for (int i = 0; i < N_STEPS; i++) ord[i] = i;
        for (int i = 1; i < N_STEPS; i++) {     // stable ascending
            int oi = ord[i];
            float kv = keys[tid * N_STEPS + oi];
            int j = i - 1;
            while (j >= 0 && keys[tid * N_STEPS + ord[j]] > kv) {
                ord[j + 1] = ord[j]; j--;
            }
            ord[j + 1] = oi;
        }
        for (int i = 0; i < N_STEPS; i++) order[tid * N_STEPS + i] = ord[i];
    }
    __syncthreads();
    float s = 0.0f;
    #pragma unroll
    for (int t = 0; t < 16; t++) {
        int idx = tid + t * 256;
        int bq = idx >> 11;
        int st = (idx >> 7) & 15;
        int dd = idx & 127;
        float va = emb[((bq    ) * N_STEPS + order[bq * N_STEPS + st]) * 128 + dd];
        float vb = emb[((2 + bq) * N_STEPS + order[(2 + bq) * N_STEPS + st]) * 128 + dd];
        float df = va - vb;
        s = fmaf(df, df, s);
    }
    sh[tid] = s;
    __syncthreads();
    for (int off = 128; off > 0; off >>= 1) {
        if (tid < off) sh[tid] += sh[tid + off];
        __syncthreads();
    }
    if (tid == 0) {
        float mse = sh[0] / 4096.0f;
        float mad = 0.5f * (fabsf(norms[0] - norms[2]) + fabsf(norms[1] - norms[3]));
        out[0] = mse + mad;
    }
}

// ---------------------------------------------------------------------------
extern "C" void kernel_launch(void* const* d_in, const int* in_sizes, int n_in,
                              void* d_out, int out_size, void* d_ws, size_t ws_size,
                              hipStream_t stream) {
    const float* a    = (const float*)d_in[0];
    const float* b    = (const float*)d_in[1];
    const float* d    = (const float*)d_in[2];
    const float* ae   = (const float*)d_in[3];
    const float* proj = (const float*)d_in[4];
    float* out = (float*)d_out;

    float* ws     = (float*)d_ws;            // needs ~40.2 MiB
    float* du     = ws + WS_DU;
    float* emb    = ws + WS_EMB;
    float* normsG = ws + WS_NORM;
    unsigned long long* pmax = (unsigned long long*)(ws + WS_PMAX);
    float* G      = ws + WS_G;
    float* S      = ws + WS_S;

    k_prep <<<128,  256, 0, stream>>>(d, du);
    k_gram <<<256,  256, 0, stream>>>(du, G);
    k_step0<<<2048, 256, 0, stream>>>(a, b, du, S, pmax);
    k_inc  <<<4,   1024, 0, stream>>>(a, b, du, G, S, pmax, ae, emb, normsG);
    k_tail <<<1,    256, 0, stream>>>(emb, normsG, proj, out);
}